// Round 5
// baseline (565.767 us; speedup 1.0000x reference)
//
#include <hip/hip_runtime.h>
#include <stdint.h>
#include <stddef.h>

#define NN 8192      // nodes
#define KD 256       // in_dim
#define CD 256       // out_dim*heads
#define FD 128       // out_dim
#define PACK_BLOCKS 1024

typedef __attribute__((ext_vector_type(4))) float f32x4;
typedef __attribute__((ext_vector_type(8))) short b16x8;

__device__ __forceinline__ unsigned short f2bf(float x) {
    unsigned int u = __float_as_uint(x);
    u += 0x7fffu + ((u >> 16) & 1u);
    return (unsigned short)(u >> 16);
}

// masked exp(leaky(sv+d)) for 8 j's (bits 0..7 of m8) -> bf16 A-frag in regs
__device__ __forceinline__ float exp_frag(
    int m8, const float4 d0, const float4 d1, float sv, b16x8* frag)
{
    const float dd[8] = {d0.x, d0.y, d0.z, d0.w, d1.x, d1.y, d1.z, d1.w};
    const float ninf = __int_as_float(0xff800000);
    float e[8]; float dp = 0.f;
#pragma unroll
    for (int k = 0; k < 8; ++k) {
        float x = sv + dd[k];
        x = fmaxf(x, 0.f) + 0.2f * fminf(x, 0.f);   // leaky_relu(0.2)
        x = (m8 & (1 << k)) ? x : ninf;              // mask: exp(-inf)=0
        const float ev = __expf(x);
        dp += ev; e[k] = ev;
    }
    union { unsigned short us[8]; b16x8 v; } pk;
#if __has_builtin(__builtin_amdgcn_cvt_pk_bf16_f32)
#pragma unroll
    for (int k = 0; k < 4; ++k) {
        auto p = __builtin_amdgcn_cvt_pk_bf16_f32(e[2 * k], e[2 * k + 1]);
        __builtin_memcpy(&pk.us[2 * k], &p, 4);
    }
#else
#pragma unroll
    for (int k = 0; k < 8; ++k) pk.us[k] = f2bf(e[k]);
#endif
    *frag = pk.v;
    return dp;
}

// ---------------------------------------------------------------------------
// Kernel 1 (fused front): blocks [0,128): T = feat @ W.T (bf16 MFMA) + scores
// + transposed bf16 Tt.  blocks [128,128+PACK_BLOCKS): adj -> bitmask stream.
// ---------------------------------------------------------------------------
__global__ __launch_bounds__(256) void k_front(
    const float* __restrict__ feat, const float* __restrict__ W,
    const float* __restrict__ asrc, const float* __restrict__ adst,
    const int* __restrict__ adj, unsigned int* __restrict__ mask,
    unsigned short* __restrict__ Tt, float* __restrict__ s_t, float* __restrict__ d_t)
{
    __shared__ unsigned short a_lds[64 * 32];    // 4KB
    __shared__ unsigned short b_lds[256 * 32];   // 16KB
    __shared__ unsigned short tr_lds[256 * 72];  // 36KB
    __shared__ float sc_lds[4][64];              // 1KB
    __shared__ float dc_lds[4][64];              // 1KB

    const int t = threadIdx.x;

    if (blockIdx.x >= 128) {
        // ---- pack path: adj int32 -> bitmask, fully streaming ----
        const int pb = blockIdx.x - 128;
        const size_t base = (size_t)pb * 16384;   // int4 units; 16384 per block
        const int4* a4 = (const int4*)adj;
#pragma unroll 4
        for (int st = 0; st < 64; ++st) {
            const size_t i4 = base + (size_t)st * 256 + t;
            const int4 v = a4[i4];
            unsigned int nib = (v.x != 0 ? 1u : 0u) | (v.y != 0 ? 2u : 0u) |
                               (v.z != 0 ? 4u : 0u) | (v.w != 0 ? 8u : 0u);
            unsigned int wd = nib << (4 * (t & 7));
            wd |= __shfl_xor(wd, 1);
            wd |= __shfl_xor(wd, 2);
            wd |= __shfl_xor(wd, 4);
            if ((t & 7) == 0) mask[i4 >> 3] = wd;
        }
        return;
    }

    // ---- transform path ----
    const int wave = t >> 6, lane = t & 63;
    const int l15 = lane & 15, quad = lane >> 4;
    const int n0 = blockIdx.x * 64;
    const int ai = t >> 2, ag = t & 3;

    f32x4 acc[4][4] = {};
    for (int kc = 0; kc < 8; ++kc) {
        const int k0 = kc * 32;
        __syncthreads();
        { // stage A: features[n0+ai][k0 + ag*8 .. +7] -> bf16
            const float* src = feat + (size_t)(n0 + ai) * KD + k0 + ag * 8;
            const float4 v0 = *(const float4*)src;
            const float4 v1 = *(const float4*)(src + 4);
            union { unsigned short us[8]; b16x8 v; } pk;
            pk.us[0] = f2bf(v0.x); pk.us[1] = f2bf(v0.y);
            pk.us[2] = f2bf(v0.z); pk.us[3] = f2bf(v0.w);
            pk.us[4] = f2bf(v1.x); pk.us[5] = f2bf(v1.y);
            pk.us[6] = f2bf(v1.z); pk.us[7] = f2bf(v1.w);
            const int slot = ag ^ ((ai >> 1) & 3);
            *(b16x8*)&a_lds[ai * 32 + slot * 8] = pk.v;
        }
        for (int p = 0; p < 4; ++p) { // stage B: W[c][k0 + g*8 .. +7]
            const int G = p * 256 + t;
            const int c = G >> 2, g = G & 3;
            const float* src = W + (size_t)c * KD + k0 + g * 8;
            const float4 v0 = *(const float4*)src;
            const float4 v1 = *(const float4*)(src + 4);
            union { unsigned short us[8]; b16x8 v; } pk;
            pk.us[0] = f2bf(v0.x); pk.us[1] = f2bf(v0.y);
            pk.us[2] = f2bf(v0.z); pk.us[3] = f2bf(v0.w);
            pk.us[4] = f2bf(v1.x); pk.us[5] = f2bf(v1.y);
            pk.us[6] = f2bf(v1.z); pk.us[7] = f2bf(v1.w);
            const int slot = g ^ ((c >> 1) & 3);
            *(b16x8*)&b_lds[c * 32 + slot * 8] = pk.v;
        }
        __syncthreads();
        b16x8 af[4], bfr[4];
        for (int mt = 0; mt < 4; ++mt) {
            const int m = mt * 16 + l15;
            af[mt] = *(const b16x8*)&a_lds[m * 32 + (quad ^ ((m >> 1) & 3)) * 8];
        }
        for (int nt = 0; nt < 4; ++nt) {
            const int c = wave * 64 + nt * 16 + l15;
            bfr[nt] = *(const b16x8*)&b_lds[c * 32 + (quad ^ ((c >> 1) & 3)) * 8];
        }
        for (int mt = 0; mt < 4; ++mt)
            for (int nt = 0; nt < 4; ++nt)
                acc[mt][nt] = __builtin_amdgcn_mfma_f32_16x16x32_bf16(
                    af[mt], bfr[nt], acc[mt][nt], 0, 0, 0);
    }

    // ---- epilogue: scores (fp32) + transposed bf16 store ----
    float aS[4], aD[4];
    for (int nt = 0; nt < 4; ++nt) {
        const int c = wave * 64 + nt * 16 + l15;
        aS[nt] = asrc[c]; aD[nt] = adst[c];
    }
    for (int mt = 0; mt < 4; ++mt)
        for (int r = 0; r < 4; ++r) {
            float vs = 0.f, vd = 0.f;
            for (int nt = 0; nt < 4; ++nt) {
                const float x = acc[mt][nt][r];
                vs += x * aS[nt]; vd += x * aD[nt];
            }
            vs += __shfl_xor(vs, 1); vd += __shfl_xor(vd, 1);
            vs += __shfl_xor(vs, 2); vd += __shfl_xor(vd, 2);
            vs += __shfl_xor(vs, 4); vd += __shfl_xor(vd, 4);
            vs += __shfl_xor(vs, 8); vd += __shfl_xor(vd, 8);
            if (l15 == 0) {
                const int nl = mt * 16 + quad * 4 + r;
                sc_lds[wave][nl] = vs; dc_lds[wave][nl] = vd;
            }
        }
    for (int mt = 0; mt < 4; ++mt)
        for (int nt = 0; nt < 4; ++nt)
            for (int r = 0; r < 4; ++r) {
                const int c = wave * 64 + nt * 16 + l15;
                const int n = mt * 16 + quad * 4 + r;
                tr_lds[c * 72 + n] = f2bf(acc[mt][nt][r]);
            }
    __syncthreads();
    if (t < 128) {
        const int n = t >> 1, h = t & 1;
        s_t[(size_t)h * NN + n0 + n] = sc_lds[h * 2][n] + sc_lds[h * 2 + 1][n];
        d_t[(size_t)h * NN + n0 + n] = dc_lds[h * 2][n] + dc_lds[h * 2 + 1][n];
    }
    for (int p = 0; p < 8; ++p) {
        const int idx = p * 256 + t;       // 2048 granules
        const int c = idx >> 3, g = idx & 7;
        *(b16x8*)(Tt + (size_t)c * NN + n0 + g * 8) = *(const b16x8*)&tr_lds[c * 72 + g * 8];
    }
}

// ---------------------------------------------------------------------------
// Kernel 2: fused masked-softmax aggregation — BARRIER-FREE, LDS-FREE.
// One wave = (head, i-half): 32 i-rows x 128 channels. A-frags computed in
// registers from mask bits + d; B-frags loaded directly from global Tt
// (L2-resident). grid=(128, jsplit), block=256.
// ---------------------------------------------------------------------------
__global__ __launch_bounds__(256, 3) void k_gat(
    const unsigned char* __restrict__ maskb, const unsigned short* __restrict__ Tt,
    const float* __restrict__ s_t, const float* __restrict__ d_t,
    float* __restrict__ num_part,   // [jsplit][NN][CD]
    float* __restrict__ den_part,   // [jsplit][2][NN]
    int njt)
{
    const int t = threadIdx.x;
    const int wave = t >> 6, lane = t & 63;
    const int l15 = lane & 15, quad = lane >> 4;
    const int h = wave >> 1, ih = wave & 1;
    const int i0 = blockIdx.x * 64 + ih * 32;
    const int chunk = blockIdx.y;
    const size_t jbase = (size_t)chunk * njt * 32;

    const int r0 = i0 + l15;          // A-frag row, mt=0
    const int r1 = i0 + 16 + l15;     // A-frag row, mt=1
    const float sv0 = s_t[(size_t)h * NN + r0];
    const float sv1 = s_t[(size_t)h * NN + r1];

    // per-lane global pointers (all L2-resident)
    const unsigned char* m0 = maskb + (size_t)r0 * (NN / 8) + (jbase >> 3) + quad;
    const unsigned char* m1 = maskb + (size_t)r1 * (NN / 8) + (jbase >> 3) + quad;
    const float* dp = d_t + (size_t)h * NN + jbase + quad * 8;
    const unsigned short* tb = Tt + (size_t)(h * 128 + l15) * NN + jbase + quad * 8;

    f32x4 acc[2][8] = {};
    float den0 = 0.f, den1 = 0.f;

    for (int jt = 0; jt < njt; ++jt) {
        const int jo = jt * 32;
        // ---- all loads first (independent; compiler schedules ahead) ----
        const int mb0 = m0[jt * 4];
        const int mb1 = m1[jt * 4];
        const float4 dv0 = *(const float4*)(dp + jo);
        const float4 dv1 = *(const float4*)(dp + jo + 4);
        b16x8 bfr[8];
#pragma unroll
        for (int nt = 0; nt < 8; ++nt)
            bfr[nt] = *(const b16x8*)(tb + (size_t)nt * 16 * NN + jo);
        // ---- A-frags in registers (masked exp-leaky) ----
        b16x8 a0, a1;
        den0 += exp_frag(mb0, dv0, dv1, sv0, &a0);
        den1 += exp_frag(mb1, dv0, dv1, sv1, &a1);
        // ---- MFMA ----
#pragma unroll
        for (int nt = 0; nt < 8; ++nt)
            acc[0][nt] = __builtin_amdgcn_mfma_f32_16x16x32_bf16(
                a0, bfr[nt], acc[0][nt], 0, 0, 0);
#pragma unroll
        for (int nt = 0; nt < 8; ++nt)
            acc[1][nt] = __builtin_amdgcn_mfma_f32_16x16x32_bf16(
                a1, bfr[nt], acc[1][nt], 0, 0, 0);
    }

    // den: reduce across the 4 quads (lane bits 4,5)
    den0 += __shfl_xor(den0, 16); den0 += __shfl_xor(den0, 32);
    den1 += __shfl_xor(den1, 16); den1 += __shfl_xor(den1, 32);
    if (quad == 0) {
        den_part[((size_t)chunk * 2 + h) * NN + r0] = den0;
        den_part[((size_t)chunk * 2 + h) * NN + r1] = den1;
    }

    float* np_ = num_part + (size_t)chunk * NN * CD;
#pragma unroll
    for (int mt = 0; mt < 2; ++mt)
#pragma unroll
        for (int nt = 0; nt < 8; ++nt)
#pragma unroll
            for (int r = 0; r < 4; ++r) {
                const int n = i0 + mt * 16 + quad * 4 + r;
                const int c = h * 128 + nt * 16 + l15;
                np_[(size_t)n * CD + c] = acc[mt][nt][r];
            }
}

// ---------------------------------------------------------------------------
// Kernel 3: combine partials, normalize, mean over heads.  grid=4096
// ---------------------------------------------------------------------------
__global__ __launch_bounds__(256) void k_combine(
    const float* __restrict__ num_part, const float* __restrict__ den_part,
    float* __restrict__ out, int jsplit)
{
    const int idx = blockIdx.x * 256 + threadIdx.x;   // NN*FD
    const int n = idx >> 7, f = idx & 127;
    const size_t row = (size_t)n * CD;
    float n0 = 0.f, n1 = 0.f, d0 = 0.f, d1 = 0.f;
    for (int c = 0; c < jsplit; ++c) {
        const size_t base = (size_t)c * NN * CD;
        n0 += num_part[base + row + f];
        n1 += num_part[base + row + 128 + f];
        d0 += den_part[((size_t)c * 2 + 0) * NN + n];
        d1 += den_part[((size_t)c * 2 + 1) * NN + n];
    }
    const float r0 = d0 != 0.f ? n0 / d0 : 0.f;
    const float r1 = d1 != 0.f ? n1 / d1 : 0.f;
    out[idx] = 0.5f * (r0 + r1);
}

// ---------------------------------------------------------------------------
extern "C" void kernel_launch(void* const* d_in, const int* in_sizes, int n_in,
                              void* d_out, int out_size, void* d_ws, size_t ws_size,
                              hipStream_t stream) {
    const float* feat = (const float*)d_in[0];
    const int*   adj  = (const int*)d_in[1];
    const float* W    = (const float*)d_in[2];
    const float* asrc = (const float*)d_in[3];
    const float* adst = (const float*)d_in[4];
    float* out = (float*)d_out;

    // ws layout: Tt 4MB | s_t/d_t/den ~0.4MB | mask 8MB @5MB | nump @13MB
    const int jsplit = (ws_size >= ((size_t)45 << 20)) ? 4 : 2;
    const int njt = (NN / jsplit) / 32;

    char* ws = (char*)d_ws;
    unsigned short* Tt = (unsigned short*)ws;                       // 4 MB
    float* s_t  = (float*)(ws + ((size_t)4 << 20));                 // 64 KB
    float* d_t  = (float*)(ws + ((size_t)4 << 20) + (64 << 10));    // 64 KB
    float* den  = (float*)(ws + ((size_t)4 << 20) + (128 << 10));   // <=256 KB
    unsigned int* mask = (unsigned int*)(ws + ((size_t)5 << 20));   // 8 MB
    float* nump = (float*)(ws + ((size_t)13 << 20));                // jsplit*8 MB

    k_front<<<128 + PACK_BLOCKS, 256, 0, stream>>>(feat, W, asrc, adst, adj,
                                                   mask, Tt, s_t, d_t);
    k_gat<<<dim3(NN / 64, jsplit), 256, 0, stream>>>((const unsigned char*)mask,
                                                     Tt, s_t, d_t, nump, den, njt);
    k_combine<<<NN * FD / 256, 256, 0, stream>>>(nump, den, out, jsplit);
}

// Round 6
// 502.072 us; speedup vs baseline: 1.1269x; 1.1269x over previous
//
#include <hip/hip_runtime.h>
#include <stdint.h>
#include <stddef.h>

#define NN 8192      // nodes
#define KD 256       // in_dim
#define CD 256       // out_dim*heads
#define FD 128       // out_dim
#define BI 32        // i-tile rows per k_gat block
#define BJ 32        // j-tile
#define PACK_BLOCKS 512

typedef __attribute__((ext_vector_type(4))) float f32x4;
typedef __attribute__((ext_vector_type(8))) short b16x8;

__device__ __forceinline__ unsigned short f2bf(float x) {
    unsigned int u = __float_as_uint(x);
    u += 0x7fffu + ((u >> 16) & 1u);
    return (unsigned short)(u >> 16);
}

// async global->LDS, 16B per lane; lds dest = wave-uniform base + lane*16
__device__ __forceinline__ void async16(const void* g, void* l) {
    __builtin_amdgcn_global_load_lds(
        (const __attribute__((address_space(1))) unsigned int*)g,
        (__attribute__((address_space(3))) unsigned int*)l, 16, 0, 0);
}

// w_j = adj ? max(Ei*Fj, Gi*Hj) : 0   (== exp(leaky_relu(s_i+d_j)) masked)
// 8 j's; pack bf16 into w LDS; returns sum.
__device__ __forceinline__ float wsel_store(
    int m8, const float4 f0, const float4 f1, const float4 h0, const float4 h1,
    float Ei, float Gi, unsigned short* wdst)
{
    const float ff[8] = {f0.x, f0.y, f0.z, f0.w, f1.x, f1.y, f1.z, f1.w};
    const float hh[8] = {h0.x, h0.y, h0.z, h0.w, h1.x, h1.y, h1.z, h1.w};
    float e[8]; float dp = 0.f;
#pragma unroll
    for (int k = 0; k < 8; ++k) {
        float w = fmaxf(Ei * ff[k], Gi * hh[k]);
        w = (m8 & (1 << k)) ? w : 0.f;
        dp += w; e[k] = w;
    }
    union { unsigned short us[8]; b16x8 v; } pk;
#if __has_builtin(__builtin_amdgcn_cvt_pk_bf16_f32)
#pragma unroll
    for (int k = 0; k < 4; ++k) {
        auto p = __builtin_amdgcn_cvt_pk_bf16_f32(e[2 * k], e[2 * k + 1]);
        __builtin_memcpy(&pk.us[2 * k], &p, 4);
    }
#else
#pragma unroll
    for (int k = 0; k < 8; ++k) pk.us[k] = f2bf(e[k]);
#endif
    *(b16x8*)wdst = pk.v;
    return dp;
}

// ---------------------------------------------------------------------------
// Kernel 1 (fused front):
//  blocks [0,128): T = feat @ W.T (bf16 MFMA) + E/G/F/H score-exponentials +
//                  tiled bf16 TB[j>>5][c][j&31]
//  blocks [128,128+PACK_BLOCKS): adj -> tiled bitmask MT[i>>5][jb][i&31]
// ---------------------------------------------------------------------------
__global__ __launch_bounds__(256) void k_front(
    const float* __restrict__ feat, const float* __restrict__ W,
    const float* __restrict__ asrc, const float* __restrict__ adst,
    const int* __restrict__ adj, unsigned char* __restrict__ MT,
    unsigned short* __restrict__ TB,
    float* __restrict__ SE, float* __restrict__ SG,
    float* __restrict__ SF, float* __restrict__ SH)
{
    __shared__ unsigned short a_lds[64 * 32];    // 4KB
    __shared__ unsigned short b_lds[256 * 32];   // 16KB
    __shared__ unsigned short tr_lds[256 * 72];  // 36KB
    __shared__ float sc_lds[4][64];              // 1KB
    __shared__ float dc_lds[4][64];              // 1KB
    __shared__ unsigned char pk_lds[1024 * 16];  // 16KB (pack path)

    const int t = threadIdx.x;

    if (blockIdx.x >= 128) {
        // ---- pack path: 16 rows of adj -> MT[I][jb][r32], streaming ----
        const int pb = blockIdx.x - 128;
        const int I = pb >> 1, half = pb & 1;
        const int row_base = I * 32 + half * 16;
        const int4* a4 = (const int4*)adj;   // NN/4 = 2048 int4 per row
#pragma unroll 4
        for (int st = 0; st < 128; ++st) {
            const int g = st * 256 + t;          // 0..32767
            const int row16 = g >> 11;           // wave-uniform
            const int j4 = g & 2047;
            const int4 v = a4[(size_t)(row_base + row16) * 2048 + j4];
            unsigned int nib = (v.x != 0 ? 1u : 0u) | (v.y != 0 ? 2u : 0u) |
                               (v.z != 0 ? 4u : 0u) | (v.w != 0 ? 8u : 0u);
            unsigned int b = nib << (4 * (t & 1));
            b |= __shfl_xor(b, 1);
            if ((t & 1) == 0) pk_lds[(j4 >> 1) * 16 + row16] = (unsigned char)b;
        }
        __syncthreads();
        unsigned int* mt32 = (unsigned int*)MT;
        const unsigned int* src = (const unsigned int*)pk_lds;
        for (int i = 0; i < 16; ++i) {
            const int w = i * 256 + t;           // 4096 words
            const int jb = w >> 2, r4 = w & 3;
            mt32[(size_t)I * 8192 + jb * 8 + half * 4 + r4] = src[w];
        }
        return;
    }

    // ---- transform path ----
    const int wave = t >> 6, lane = t & 63;
    const int l15 = lane & 15, quad = lane >> 4;
    const int n0 = blockIdx.x * 64;
    const int ai = t >> 2, ag = t & 3;

    f32x4 acc[4][4] = {};
    for (int kc = 0; kc < 8; ++kc) {
        const int k0 = kc * 32;
        __syncthreads();
        { // stage A: features[n0+ai][k0 + ag*8 .. +7] -> bf16
            const float* src = feat + (size_t)(n0 + ai) * KD + k0 + ag * 8;
            const float4 v0 = *(const float4*)src;
            const float4 v1 = *(const float4*)(src + 4);
            union { unsigned short us[8]; b16x8 v; } pk;
            pk.us[0] = f2bf(v0.x); pk.us[1] = f2bf(v0.y);
            pk.us[2] = f2bf(v0.z); pk.us[3] = f2bf(v0.w);
            pk.us[4] = f2bf(v1.x); pk.us[5] = f2bf(v1.y);
            pk.us[6] = f2bf(v1.z); pk.us[7] = f2bf(v1.w);
            const int slot = ag ^ ((ai >> 1) & 3);
            *(b16x8*)&a_lds[ai * 32 + slot * 8] = pk.v;
        }
        for (int p = 0; p < 4; ++p) { // stage B: W[c][k0 + g*8 .. +7]
            const int G = p * 256 + t;
            const int c = G >> 2, g = G & 3;
            const float* src = W + (size_t)c * KD + k0 + g * 8;
            const float4 v0 = *(const float4*)src;
            const float4 v1 = *(const float4*)(src + 4);
            union { unsigned short us[8]; b16x8 v; } pk;
            pk.us[0] = f2bf(v0.x); pk.us[1] = f2bf(v0.y);
            pk.us[2] = f2bf(v0.z); pk.us[3] = f2bf(v0.w);
            pk.us[4] = f2bf(v1.x); pk.us[5] = f2bf(v1.y);
            pk.us[6] = f2bf(v1.z); pk.us[7] = f2bf(v1.w);
            const int slot = g ^ ((c >> 1) & 3);
            *(b16x8*)&b_lds[c * 32 + slot * 8] = pk.v;
        }
        __syncthreads();
        b16x8 af[4], bfr[4];
        for (int mt = 0; mt < 4; ++mt) {
            const int m = mt * 16 + l15;
            af[mt] = *(const b16x8*)&a_lds[m * 32 + (quad ^ ((m >> 1) & 3)) * 8];
        }
        for (int nt = 0; nt < 4; ++nt) {
            const int c = wave * 64 + nt * 16 + l15;
            bfr[nt] = *(const b16x8*)&b_lds[c * 32 + (quad ^ ((c >> 1) & 3)) * 8];
        }
        for (int mt = 0; mt < 4; ++mt)
            for (int nt = 0; nt < 4; ++nt)
                acc[mt][nt] = __builtin_amdgcn_mfma_f32_16x16x32_bf16(
                    af[mt], bfr[nt], acc[mt][nt], 0, 0, 0);
    }

    // ---- epilogue: scores (fp32) + tiled bf16 store ----
    float aS[4], aD[4];
    for (int nt = 0; nt < 4; ++nt) {
        const int c = wave * 64 + nt * 16 + l15;
        aS[nt] = asrc[c]; aD[nt] = adst[c];
    }
    for (int mt = 0; mt < 4; ++mt)
        for (int r = 0; r < 4; ++r) {
            float vs = 0.f, vd = 0.f;
            for (int nt = 0; nt < 4; ++nt) {
                const float x = acc[mt][nt][r];
                vs += x * aS[nt]; vd += x * aD[nt];
            }
            vs += __shfl_xor(vs, 1); vd += __shfl_xor(vd, 1);
            vs += __shfl_xor(vs, 2); vd += __shfl_xor(vd, 2);
            vs += __shfl_xor(vs, 4); vd += __shfl_xor(vd, 4);
            vs += __shfl_xor(vs, 8); vd += __shfl_xor(vd, 8);
            if (l15 == 0) {
                const int nl = mt * 16 + quad * 4 + r;
                sc_lds[wave][nl] = vs; dc_lds[wave][nl] = vd;
            }
        }
    for (int mt = 0; mt < 4; ++mt)
        for (int nt = 0; nt < 4; ++nt)
            for (int r = 0; r < 4; ++r) {
                const int c = wave * 64 + nt * 16 + l15;
                const int n = mt * 16 + quad * 4 + r;
                tr_lds[c * 72 + n] = f2bf(acc[mt][nt][r]);
            }
    __syncthreads();
    if (t < 128) {
        const int n = t >> 1, h = t & 1;
        const float s = sc_lds[h * 2][n] + sc_lds[h * 2 + 1][n];
        const float d = dc_lds[h * 2][n] + dc_lds[h * 2 + 1][n];
        SE[(size_t)h * NN + n0 + n] = __expf(s);
        SG[(size_t)h * NN + n0 + n] = __expf(0.2f * s);
        SF[(size_t)h * NN + n0 + n] = __expf(d);
        SH[(size_t)h * NN + n0 + n] = __expf(0.2f * d);
    }
    for (int p = 0; p < 8; ++p) {
        const int idx = p * 256 + t;       // 2048 granules
        const int c = idx >> 3, g = idx & 7;
        // TB[(n0+g*8)>>5][c][(n0+g*8)&31]
        unsigned short* dst = TB + ((size_t)((n0 >> 5) + (g >> 2))) * 8192
                              + c * 32 + (g & 3) * 8;
        *(b16x8*)dst = *(const b16x8*)&tr_lds[c * 72 + g * 8];
    }
}

// ---------------------------------------------------------------------------
// Kernel 2: fused masked-softmax aggregation. R4 pipeline + tiled TB/MT +
// exp-free select math. LDS = 40960 -> 4 blocks/CU. grid=(256, jsplit).
// ---------------------------------------------------------------------------
__global__ __launch_bounds__(256, 4) void k_gat(
    const unsigned char* __restrict__ MT, const unsigned short* __restrict__ TB,
    const float* __restrict__ SE, const float* __restrict__ SG,
    const float* __restrict__ SF, const float* __restrict__ SH,
    float* __restrict__ num_part,   // [jsplit][NN][CD]
    float* __restrict__ den_part,   // [jsplit][2][NN]
    int njt)
{
    __shared__ unsigned short tt_lds[2][256 * 32];   // 32KB dbuf
    __shared__ unsigned short w_lds[2][2][32][32];   // 8KB dbuf

    const int t = threadIdx.x;
    const int wave = t >> 6, lane = t & 63;
    const int l15 = lane & 15, quad = lane >> 4;
    const int i0 = blockIdx.x * BI;
    const int chunk = blockIdx.y;
    const size_t jbase = (size_t)chunk * njt * BJ;

    // w-compute mapping: head / row / j-granule(8)
    const int eh = t >> 7;
    const int wi = (t >> 2) & 31;
    const int g4 = t & 3;
    const int gi = i0 + wi;
    const float Ei = SE[(size_t)eh * NN + gi];
    const float Gi = SG[(size_t)eh * NN + gi];
    const int wslot = (g4 ^ (wi & 3) ^ ((wi >> 2) & 3)) * 8;

    // mfma mapping: head / f-half per wave
    const int mh = wave >> 1, fh = wave & 1;
    const int cb = mh * 128 + fh * 64;

    f32x4 acc[2][4] = {};
    float den = 0.f;

    // tiled pointers
    const unsigned short* tb0 = TB + (jbase >> 5) * 8192;         // tile jt at +jt*8192
    const unsigned char* mrow = MT + ((size_t)(i0 >> 5)) * 32768
                                + (jbase >> 3) * 32 + g4 * 32 + wi; // + jt*128
    const float* fp = SF + (size_t)eh * NN + jbase + g4 * 8;
    const float* hp = SH + (size_t)eh * NN + jbase + g4 * 8;

    // ---- prologue: tile0 asyncs + tile0/1 scalars + w[0] ----
    for (int p = 0; p < 4; ++p) {
        const int G = (p * 4 + wave) * 64 + lane;
        const int c = G >> 2;
        const int g = (G & 3) ^ ((c >> 1) & 3);      // lane-perm inside 64B row seg
        async16(tb0 + (size_t)c * 32 + g * 8,
                (char*)&tt_lds[0][0] + (size_t)(p * 4 + wave) * 1024);
    }
    __builtin_amdgcn_sched_barrier(0);
    int cM = mrow[0];
    float4 cF0 = *(const float4*)(fp),     cF1 = *(const float4*)(fp + 4);
    float4 cH0 = *(const float4*)(hp),     cH1 = *(const float4*)(hp + 4);
    int nM; float4 nF0, nF1, nH0, nH1;
    {
        const int j1 = (njt > 1) ? 1 : 0;
        nM = mrow[j1 * 128];
        nF0 = *(const float4*)(fp + j1 * BJ); nF1 = *(const float4*)(fp + j1 * BJ + 4);
        nH0 = *(const float4*)(hp + j1 * BJ); nH1 = *(const float4*)(hp + j1 * BJ + 4);
        den += wsel_store(cM, cF0, cF1, cH0, cH1, Ei, Gi, &w_lds[0][eh][wi][wslot]);
        cM = nM; cF0 = nF0; cF1 = nF1; cH0 = nH0; cH1 = nH1;
    }
    asm volatile("s_waitcnt vmcnt(5) lgkmcnt(0)\n\ts_barrier" ::: "memory");

    // ---- main loop: ONE barrier per iteration ----
    for (int jt = 0; jt < njt; ++jt) {
        const int cur = jt & 1, nxt = cur ^ 1;
        // 1. fragment ds_reads from [cur]
        b16x8 af[2], bfr[4];
        for (int mt = 0; mt < 2; ++mt) {
            const int m = mt * 16 + l15;
            af[mt] = *(const b16x8*)
                &w_lds[cur][mh][m][(quad ^ (m & 3) ^ ((m >> 2) & 3)) * 8];
        }
        for (int nt = 0; nt < 4; ++nt) {
            const int c = cb + nt * 16 + l15;
            bfr[nt] = *(const b16x8*)&tt_lds[cur][c * 32 + (quad ^ ((c >> 1) & 3)) * 8];
        }
        // 2. async TB tile jt+1 (clamped) -> [nxt]; each instr = 1KB contiguous
        const unsigned short* tbn = tb0 + (size_t)((jt + 1 < njt) ? jt + 1 : jt) * 8192;
        for (int p = 0; p < 4; ++p) {
            const int G = (p * 4 + wave) * 64 + lane;
            const int c = G >> 2;
            const int g = (G & 3) ^ ((c >> 1) & 3);
            async16(tbn + (size_t)c * 32 + g * 8,
                    (char*)&tt_lds[nxt][0] + (size_t)(p * 4 + wave) * 1024);
        }
        __builtin_amdgcn_sched_barrier(0);   // pin FIFO: asyncs before prefetch
        // 3. mask/F/H prefetch, 2 tiles ahead (clamped) — 5 loads stay in flight
        const int j2 = (jt + 2 < njt) ? jt + 2 : njt - 1;
        nM = mrow[j2 * 128];
        nF0 = *(const float4*)(fp + j2 * BJ); nF1 = *(const float4*)(fp + j2 * BJ + 4);
        nH0 = *(const float4*)(hp + j2 * BJ); nH1 = *(const float4*)(hp + j2 * BJ + 4);
        // 4. w for tile jt+1 -> w_lds[nxt] (no VMEM wait: inputs already in regs)
        const float dpv = wsel_store(cM, cF0, cF1, cH0, cH1, Ei, Gi,
                                     &w_lds[nxt][eh][wi][wslot]);
        if (jt + 1 < njt) den += dpv;
        // 5. MFMA tile jt
        for (int mt = 0; mt < 2; ++mt)
            for (int nt = 0; nt < 4; ++nt)
                acc[mt][nt] = __builtin_amdgcn_mfma_f32_16x16x32_bf16(
                    af[mt], bfr[nt], acc[mt][nt], 0, 0, 0);
        // 6. rotate; barrier drains this iter's 4 asyncs, keeps 5 prefetches
        cM = nM; cF0 = nF0; cF1 = nF1; cH0 = nH0; cH1 = nH1;
        asm volatile("s_waitcnt vmcnt(5) lgkmcnt(0)\n\ts_barrier" ::: "memory");
    }

    // den reduce over g4 lanes (lane bits 0..1)
    float dv = den;
    dv += __shfl_xor(dv, 1); dv += __shfl_xor(dv, 2);
    if (g4 == 0)
        den_part[((size_t)chunk * 2 + eh) * NN + gi] = dv;

    float* np_ = num_part + (size_t)chunk * NN * CD;
    for (int mt = 0; mt < 2; ++mt)
        for (int nt = 0; nt < 4; ++nt)
            for (int r = 0; r < 4; ++r) {
                const int n = i0 + mt * 16 + quad * 4 + r;
                const int c = cb + nt * 16 + l15;
                np_[(size_t)n * CD + c] = acc[mt][nt][r];
            }
}

// ---------------------------------------------------------------------------
// Kernel 3: combine partials, normalize, mean over heads.  grid=4096
// ---------------------------------------------------------------------------
__global__ __launch_bounds__(256) void k_combine(
    const float* __restrict__ num_part, const float* __restrict__ den_part,
    float* __restrict__ out, int jsplit)
{
    const int idx = blockIdx.x * 256 + threadIdx.x;   // NN*FD
    const int n = idx >> 7, f = idx & 127;
    const size_t row = (size_t)n * CD;
    float n0 = 0.f, n1 = 0.f, d0 = 0.f, d1 = 0.f;
    for (int c = 0; c < jsplit; ++c) {
        const size_t base = (size_t)c * NN * CD;
        n0 += num_part[base + row + f];
        n1 += num_part[base + row + 128 + f];
        d0 += den_part[((size_t)c * 2 + 0) * NN + n];
        d1 += den_part[((size_t)c * 2 + 1) * NN + n];
    }
    const float r0 = d0 != 0.f ? n0 / d0 : 0.f;
    const float r1 = d1 != 0.f ? n1 / d1 : 0.f;
    out[idx] = 0.5f * (r0 + r1);
}

// ---------------------------------------------------------------------------
extern "C" void kernel_launch(void* const* d_in, const int* in_sizes, int n_in,
                              void* d_out, int out_size, void* d_ws, size_t ws_size,
                              hipStream_t stream) {
    const float* feat = (const float*)d_in[0];
    const int*   adj  = (const int*)d_in[1];
    const float* W    = (const float*)d_in[2];
    const float* asrc = (const float*)d_in[3];
    const float* adst = (const float*)d_in[4];
    float* out = (float*)d_out;

    const int jsplit = (ws_size >= ((size_t)45 << 20)) ? 4 : 2;
    const int njt = (NN / jsplit) / BJ;

    char* ws = (char*)d_ws;
    unsigned short* TB = (unsigned short*)ws;                        // 4 MB tiled T
    float* SE = (float*)(ws + ((size_t)4 << 20));                    // 64 KB
    float* SG = (float*)(ws + ((size_t)4 << 20) + (64 << 10));       // 64 KB
    float* SF = (float*)(ws + ((size_t)4 << 20) + (128 << 10));      // 64 KB
    float* SH = (float*)(ws + ((size_t)4 << 20) + (192 << 10));      // 64 KB
    float* den = (float*)(ws + ((size_t)4 << 20) + (256 << 10));     // <=256 KB
    unsigned char* MT = (unsigned char*)(ws + ((size_t)5 << 20));    // 8 MB tiled mask
    float* nump = (float*)(ws + ((size_t)13 << 20));                 // jsplit*8 MB

    k_front<<<128 + PACK_BLOCKS, 256, 0, stream>>>(feat, W, asrc, adst, adj,
                                                   MT, TB, SE, SG, SF, SH);
    k_gat<<<dim3(NN / BI, jsplit), 256, 0, stream>>>(MT, TB, SE, SG, SF, SH,
                                                     nump, den, njt);
    k_combine<<<NN * FD / 256, 256, 0, stream>>>(nump, den, out, jsplit);
}